// Round 9
// baseline (186.562 us; speedup 1.0000x reference)
//
#include <hip/hip_runtime.h>
#include <hip/hip_bf16.h>
#include <math.h>

#define BB 8
#define HH 512
#define WW 512
#define NPIX (BB * HH * WW)        // 2097152
#define HWPIX (HH * WW)            // 262144 = 2^18
#define PBUD 1048576               // P
#define RAD 7                      // 15//2
#define NB (NPIX / 256)            // 8192 rank blocks of 256 pixels
#define NMLP (NPIX / 128)          // 16384 MLP tiles of 128 pixels

// LDS map (k_mlp): [0,32768) H1 tile (128px x 128j bf16, swz ^(px&15)<<4)
//   [32768,34816) X rows 16B/px; [34816,34832) zero row; [34832,34840) flags
//   [32768,36864) PART overlay f32[8][128] (X region dead after phase 1)
#define XOFF  32768
#define ZROW  (XOFF + 2048)
#define FLAG0 (XOFF + 2080)
#define PART  XOFF

typedef __attribute__((ext_vector_type(4))) float f32x4;
typedef __attribute__((ext_vector_type(8))) short short8;
typedef __attribute__((ext_vector_type(2))) unsigned int u32x2;
typedef __attribute__((ext_vector_type(4))) unsigned int u32x4;

__device__ __forceinline__ unsigned short f2bf(float f) {
    unsigned int u = __float_as_uint(f);
    unsigned int r = (u + 0x7fffu + ((u >> 16) & 1u)) >> 16;   // RNE
    return (unsigned short)r;
}

// packed f32 pair -> bf16x2 (compiler emits v_cvt_pk_bf16_f32)
__device__ __forceinline__ unsigned int pkbf(float a, float b) {
    __hip_bfloat162 h = __float22bfloat162_rn(make_float2(a, b));
    return *(unsigned int*)&h;
}

// ---- K0: weight prep (unchanged, layouts verified rounds 5-7) ----------------
// w2f[((jc*4+ks)*64+l)*8+e] = W2[k][j], j=jc*16+(l&15), k=ks*32+((l>>4)&3)*8+e
// w1f[(fi*64+l)*8+e] = W1'[k][j], j=fi*16+(l&15), k=((l>>4)&3)*8+e  (k4=b1, k>4=0)
__global__ void k_prep(const float* __restrict__ w2, const float* __restrict__ w1,
                       const float* __restrict__ b1,
                       unsigned short* __restrict__ w2f, unsigned short* __restrict__ w1f) {
    int i = blockIdx.x * 256 + threadIdx.x;   // 20480 threads
    if (i < 16384) {
        int e  = i & 7;
        int l  = (i >> 3) & 63;
        int ks = (i >> 9) & 3;
        int jc = i >> 11;
        int j = jc * 16 + (l & 15);
        int k = ks * 32 + ((l >> 4) & 3) * 8 + e;
        w2f[i] = f2bf(w2[k * 128 + j]);
    } else {
        int i2 = i - 16384;                   // 4096 elements
        int e  = i2 & 7;
        int l  = (i2 >> 3) & 63;
        int fi = i2 >> 9;                     // 0..7
        int j = fi * 16 + (l & 15);
        int k = ((l >> 4) & 3) * 8 + e;       // 0..31
        float v = (k < 4) ? w1[k * 128 + j] : ((k == 4) ? b1[j] : 0.0f);
        w1f[i2] = f2bf(v);
    }
}

// ---------------- K1: mask + horizontal dilate --------------------------------
__global__ void k_rowdil(const float* __restrict__ lr, unsigned char* __restrict__ rowdil) {
    int p = blockIdx.x * 256 + threadIdx.x;
    int w = p & (WW - 1);
    int row0 = p - w;
    int lo = w - RAD; if (lo < 0) lo = 0;
    int hi = w + RAD; if (hi > WW - 1) hi = WW - 1;
    unsigned char any = 0;
    for (int x = lo; x <= hi; ++x) {
        float v = lr[row0 + x];
        any |= (unsigned char)(v > 0.01f && v < 0.99f);
    }
    rowdil[p] = any;
}

// ------- K2: vertical dilate + per-256-block count + intra-block rank byte ----
__global__ void k_coldil(const unsigned char* __restrict__ rowdil,
                         unsigned char* __restrict__ dm,
                         unsigned char* __restrict__ rankb,
                         int* __restrict__ gsum) {
    int p = blockIdx.x * 256 + threadIdx.x;
    int h = (p >> 9) & (HH - 1);
    int lo = h - RAD; if (lo < 0) lo = 0;
    int hi = h + RAD; if (hi > HH - 1) hi = HH - 1;
    lo -= h; hi -= h;
    unsigned char any = 0;
    for (int d = lo; d <= hi; ++d) any |= rowdil[p + d * WW];
    dm[p] = any;

    unsigned long long bal = __ballot(any != 0);
    __shared__ int wsum[4];
    int lane = threadIdx.x & 63;
    int wid  = threadIdx.x >> 6;
    if (lane == 0) wsum[wid] = __popcll(bal);
    __syncthreads();
    int pre = __popcll(bal & ((1ull << lane) - 1ull));
    int woff = 0;
    for (int i = 0; i < wid; ++i) woff += wsum[i];
    rankb[p] = (unsigned char)(woff + pre);
    if (threadIdx.x == 0) gsum[blockIdx.x] = wsum[0] + wsum[1] + wsum[2] + wsum[3];
}

// ---------------- K3: exclusive scan of 8192 block counts (one block) ---------
__global__ void k_scan(const int* __restrict__ gsum, int* __restrict__ goff) {
    __shared__ int tsum[1024];
    int t = threadIdx.x;
    int base = t * 8;
    int v[8];
    int s = 0;
#pragma unroll
    for (int i = 0; i < 8; ++i) { v[i] = gsum[base + i]; s += v[i]; }
    tsum[t] = s;
    __syncthreads();
    for (int off = 1; off < 1024; off <<= 1) {
        int x = tsum[t];
        int y = (t >= off) ? tsum[t - off] : 0;
        __syncthreads();
        tsum[t] = x + y;
        __syncthreads();
    }
    int run = (t == 0) ? 0 : tsum[t - 1];
#pragma unroll
    for (int i = 0; i < 8; ++i) { goff[base + i] = run; run += v[i]; }
}

// ---------------- K4: 8-wave MFMA MLP, wave w owns j-slice jc=w ---------------
__global__ __launch_bounds__(512, 6)
void k_mlp(const float* __restrict__ image, const float* __restrict__ lr,
           const unsigned short* __restrict__ w1f, const unsigned short* __restrict__ w2f,
           const float* __restrict__ b2, const float* __restrict__ w3,
           const float* __restrict__ b3,
           const unsigned char* __restrict__ dm, const unsigned char* __restrict__ rankb,
           const int* __restrict__ goff, float* __restrict__ out) {
    __shared__ __align__(16) char lds[36864];
    int p0 = blockIdx.x * 128;
    int t  = threadIdx.x;
    int w  = t >> 6;
    int l  = t & 63;
    int lr16 = l & 15;
    int lh   = (l >> 4) & 3;

    // L1 A-fragment for this wave's j-tile (fi = w): issue early, L2-hot
    const short8* wf1 = (const short8*)w1f;
    short8 a1 = wf1[w * 64 + l];
    float b2v = b2[w * 16 + lr16];
    float w3v = w3[w * 16 + lr16];
    float b3v = b3[0];

    // ---- phase 0: selection + X staging (t<128) + flags ----
    bool  sel = false;
    float lrv = 0.f;
    if (t < 128) {
        int p = p0 + t;
        lrv = lr[p];
        sel = dm[p] && (goff[p >> 8] + (int)rankb[p] < PBUD);
        size_t bimg = (size_t)(p >> 18) * 3 * HWPIX + (p & (HWPIX - 1));
        float x0 = image[bimg];
        float x1 = image[bimg + HWPIX];
        float x2 = image[bimg + 2 * HWPIX];
        float x3 = 2.0f * lrv - 1.0f;
        u32x4 d0 = { pkbf(x0, x1), pkbf(x2, x3), pkbf(1.0f, 0.0f), 0u };
        *(u32x4*)(lds + XOFF + t * 16) = d0;
    }
    if (t == 128) *(u32x4*)(lds + ZROW) = (u32x4){0u, 0u, 0u, 0u};
    if (t < 128) {   // waves 0,1 fully active -> wave-wide ballot is safe
        unsigned long long bal = __ballot(sel);
        if (l == 0) *(int*)(lds + FLAG0 + w * 4) = (bal != 0ull) ? 1 : 0;
    }
    __syncthreads();
    int any = *(const int*)(lds + FLAG0) | *(const int*)(lds + FLAG0 + 4);
    if (!any) {
        if (t < 128) out[p0 + t] = lrv;
        return;
    }

    // ---- phase 1: H1^T[j=w*16..][px] = W1' @ X' (K=32, bias in k=4) ----
    // B-frag: lanes lh==0 carry k=0..7 (x0..x3,1,0,0,0); lh>0 read shared zero row.
#pragma unroll
    for (int jc = 0; jc < 8; ++jc) {
        int px = jc * 16 + lr16;
        const char* xaddr = (lh == 0) ? (lds + XOFF + px * 16) : (lds + ZROW);
        short8 xb = *(const short8*)xaddr;
        f32x4 c = {0.f, 0.f, 0.f, 0.f};
        c = __builtin_amdgcn_mfma_f32_16x16x32_bf16(a1, xb, c, 0, 0, 0);
        int j0 = w * 16 + lh * 4;
        u32x2 u = { pkbf(fmaxf(c[0], 0.f), fmaxf(c[1], 0.f)),
                    pkbf(fmaxf(c[2], 0.f), fmaxf(c[3], 0.f)) };
        *(u32x2*)(lds + (((px << 8) | (j0 << 1)) ^ (lr16 << 4))) = u;
    }

    // B-fragments for this wave's jc=w (4 KB/wave, L1/L2-hot); issue before
    // the barrier so VMEM latency overlaps the barrier wait.
    const short8* wf2 = (const short8*)w2f;
    short8 bf[4];
#pragma unroll
    for (int ks = 0; ks < 4; ++ks) bf[ks] = wf2[(w * 4 + ks) * 64 + l];
    __syncthreads();

    // ---- phase 2: OUT[px][j=w*16+lr16] for all 128 px (8 m-tiles) ----
    f32x4 acc[8];
#pragma unroll
    for (int mt = 0; mt < 8; ++mt) acc[mt] = (f32x4){b2v, b2v, b2v, b2v};
#pragma unroll
    for (int mt = 0; mt < 8; ++mt) {
#pragma unroll
        for (int ks = 0; ks < 4; ++ks) {
            int row = mt * 16 + lr16;
            short8 af = *(const short8*)(lds + ((((row << 8) | (ks << 6) | (lh << 4))) ^ (lr16 << 4)));
            acc[mt] = __builtin_amdgcn_mfma_f32_16x16x32_bf16(af, bf[ks], acc[mt], 0, 0, 0);
        }
    }

    // ---- epilogue: relu + dot(w3) over this wave's 16 j -> PART[w][px] ----
#pragma unroll
    for (int mt = 0; mt < 8; ++mt) {
#pragma unroll
        for (int r = 0; r < 4; ++r) {
            float part = fmaxf(acc[mt][r], 0.f) * w3v;
            part += __shfl_xor(part, 1);
            part += __shfl_xor(part, 2);
            part += __shfl_xor(part, 4);
            part += __shfl_xor(part, 8);
            if (lr16 == 0) {
                int px = mt * 16 + lh * 4 + r;   // C/D: row = (lane>>4)*4 + reg
                *(float*)(lds + PART + w * 512 + px * 4) = part;
            }
        }
    }
    __syncthreads();
    if (t < 128) {
        float s = b3v;
#pragma unroll
        for (int ww = 0; ww < 8; ++ww) s += *(const float*)(lds + PART + ww * 512 + t * 4);
        out[p0 + t] = sel ? (1.0f / (1.0f + __expf(-s))) : lrv;
    }
}

// ---------------- launcher ----------------------------------------------------
extern "C" void kernel_launch(void* const* d_in, const int* in_sizes, int n_in,
                              void* d_out, int out_size, void* d_ws, size_t ws_size,
                              hipStream_t stream) {
    const float* image = (const float*)d_in[0];
    const float* lr    = (const float*)d_in[1];
    const float* w1    = (const float*)d_in[2];
    const float* b1    = (const float*)d_in[3];
    const float* w2    = (const float*)d_in[4];
    const float* b2    = (const float*)d_in[5];
    const float* w3    = (const float*)d_in[6];
    const float* b3    = (const float*)d_in[7];
    float* out = (float*)d_out;

    char* ws = (char*)d_ws;
    unsigned char* rowdil = (unsigned char*)ws;                         // NPIX
    unsigned char* dm     = (unsigned char*)(ws + (size_t)NPIX);        // NPIX
    unsigned char* rankb  = (unsigned char*)(ws + 2 * (size_t)NPIX);    // NPIX
    int* gsum             = (int*)(ws + 3 * (size_t)NPIX);              // NB
    int* goff             = (int*)(ws + 3 * (size_t)NPIX + NB * 4);     // NB
    unsigned short* w2f   = (unsigned short*)(ws + 3 * (size_t)NPIX + 2 * NB * 4); // 16384 bf16
    unsigned short* w1f   = w2f + 16384;                                           // 4096 bf16

    k_prep  <<<80, 256, 0, stream>>>(w2, w1, b1, w2f, w1f);
    k_rowdil<<<NPIX / 256, 256, 0, stream>>>(lr, rowdil);
    k_coldil<<<NB, 256, 0, stream>>>(rowdil, dm, rankb, gsum);
    k_scan  <<<1, 1024, 0, stream>>>(gsum, goff);
    k_mlp   <<<NMLP, 512, 0, stream>>>(image, lr, w1f, w2f, b2, w3, b3,
                                       dm, rankb, goff, out);
}

// Round 12
// 135.794 us; speedup vs baseline: 1.3739x; 1.3739x over previous
//
#include <hip/hip_runtime.h>
#include <hip/hip_bf16.h>
#include <math.h>

#define BB 8
#define HH 512
#define WW 512
#define NPIX (BB * HH * WW)        // 2097152
#define HWPIX (HH * WW)            // 262144 = 2^18
#define PBUD 1048576               // P
#define RAD 7                      // 15//2
#define NB (NPIX / 256)            // 8192 rank blocks of 256 pixels
#define NMLP (NPIX / 128)          // 16384 MLP tiles of 128 pixels

typedef __attribute__((ext_vector_type(4))) float f32x4;
typedef __attribute__((ext_vector_type(8))) short short8;
typedef __attribute__((ext_vector_type(4))) unsigned int u32x4;

__device__ __forceinline__ unsigned short f2bf(float f) {
    unsigned int u = __float_as_uint(f);
    unsigned int r = (u + 0x7fffu + ((u >> 16) & 1u)) >> 16;   // RNE
    return (unsigned short)r;
}

// packed f32 pair -> bf16x2 (compiler emits v_cvt_pk_bf16_f32)
__device__ __forceinline__ unsigned int pkbf(float a, float b) {
    __hip_bfloat162 h = __float22bfloat162_rn(make_float2(a, b));
    return *(unsigned int*)&h;
}

// ---- K0: W2 [k][j] fp32 -> bf16 B-fragments in exact MFMA lane order --------
// w2f[((jc*4+ks)*64 + l)*8 + e] = bf16(W2[k][j]), j=jc*16+(l&15), k=ks*32+((l>>4)&3)*8+e
__global__ void k_prep_w2(const float* __restrict__ w2, unsigned short* __restrict__ w2f) {
    int i = blockIdx.x * 256 + threadIdx.x;   // 16384 threads
    int e  = i & 7;
    int l  = (i >> 3) & 63;
    int ks = (i >> 9) & 3;
    int jc = i >> 11;
    int j = jc * 16 + (l & 15);
    int k = ks * 32 + ((l >> 4) & 3) * 8 + e;
    w2f[i] = f2bf(w2[k * 128 + j]);
}

// ---------------- K1: mask + horizontal dilate --------------------------------
__global__ void k_rowdil(const float* __restrict__ lr, unsigned char* __restrict__ rowdil) {
    int p = blockIdx.x * 256 + threadIdx.x;
    int w = p & (WW - 1);
    int row0 = p - w;
    int lo = w - RAD; if (lo < 0) lo = 0;
    int hi = w + RAD; if (hi > WW - 1) hi = WW - 1;
    unsigned char any = 0;
    for (int x = lo; x <= hi; ++x) {
        float v = lr[row0 + x];
        any |= (unsigned char)(v > 0.01f && v < 0.99f);
    }
    rowdil[p] = any;
}

// ------- K2: vertical dilate + per-256-block count + intra-block rank byte ----
__global__ void k_coldil(const unsigned char* __restrict__ rowdil,
                         unsigned char* __restrict__ dm,
                         unsigned char* __restrict__ rankb,
                         int* __restrict__ gsum) {
    int p = blockIdx.x * 256 + threadIdx.x;
    int h = (p >> 9) & (HH - 1);
    int lo = h - RAD; if (lo < 0) lo = 0;
    int hi = h + RAD; if (hi > HH - 1) hi = HH - 1;
    lo -= h; hi -= h;
    unsigned char any = 0;
    for (int d = lo; d <= hi; ++d) any |= rowdil[p + d * WW];
    dm[p] = any;

    unsigned long long bal = __ballot(any != 0);
    __shared__ int wsum[4];
    int lane = threadIdx.x & 63;
    int wid  = threadIdx.x >> 6;
    if (lane == 0) wsum[wid] = __popcll(bal);
    __syncthreads();
    int pre = __popcll(bal & ((1ull << lane) - 1ull));
    int woff = 0;
    for (int i = 0; i < wid; ++i) woff += wsum[i];
    rankb[p] = (unsigned char)(woff + pre);
    if (threadIdx.x == 0) gsum[blockIdx.x] = wsum[0] + wsum[1] + wsum[2] + wsum[3];
}

// ---------------- K3: exclusive scan of 8192 block counts (one block) ---------
__global__ void k_scan(const int* __restrict__ gsum, int* __restrict__ goff) {
    __shared__ int tsum[1024];
    int t = threadIdx.x;
    int base = t * 8;
    int v[8];
    int s = 0;
#pragma unroll
    for (int i = 0; i < 8; ++i) { v[i] = gsum[base + i]; s += v[i]; }
    tsum[t] = s;
    __syncthreads();
    for (int off = 1; off < 1024; off <<= 1) {
        int x = tsum[t];
        int y = (t >= off) ? tsum[t - off] : 0;
        __syncthreads();
        tsum[t] = x + y;
        __syncthreads();
    }
    int run = (t == 0) ? 0 : tsum[t - 1];
#pragma unroll
    for (int i = 0; i < 8; ++i) { goff[base + i] = run; run += v[i]; }
}

// ---------------- K4: MFMA MLP over 128-pixel tiles (round-5 structure) -------
// LDS: H1 tile only — 128 rows x 128 bf16 (256B rows), XOR-swizzled:
//   byte ^= (row & 15) << 4   (bijective within each 256B row)
// B-operand straight from global w2f (L1/L2-resident, fragment-ordered).
// Diff vs round-5 104us baseline: pkbf H1 packing (v_cvt_pk_bf16_f32),
// b2 folded into acc init. Everything else identical.
__global__ __launch_bounds__(256, 4)
void k_mlp(const float* __restrict__ image, const float* __restrict__ lr,
           const float* __restrict__ w1, const float* __restrict__ b1,
           const unsigned short* __restrict__ w2f, const float* __restrict__ b2,
           const float* __restrict__ w3, const float* __restrict__ b3,
           const unsigned char* __restrict__ dm, const unsigned char* __restrict__ rankb,
           const int* __restrict__ goff, float* __restrict__ out) {
    __shared__ __align__(16) char lds[32768];
    __shared__ int s_any;
    int g  = blockIdx.x;
    int p0 = g * 128;
    int t  = threadIdx.x;

    // ---- phase 0: any selected pixel in this 128-px tile? ----
    if (t == 0) s_any = 0;
    __syncthreads();
    if (t < 128) {
        int p = p0 + t;
        if (dm[p] && (goff[p >> 8] + (int)rankb[p] < PBUD)) s_any = 1;
    }
    __syncthreads();
    if (!s_any) {
        if (t < 128) out[p0 + t] = lr[p0 + t];
        return;
    }

    // ---- phase 1: layer 1 (4 -> 128) -> bf16 H1 in LDS (swizzled) ----
    {
        int px = t & 127;                  // pixel row in tile
        // readfirstlane -> SGPR: w1/b1 addresses provably uniform -> s_load
        int jh = __builtin_amdgcn_readfirstlane(t >> 7);   // 0 or 1
        int p  = p0 + px;
        float lrv = lr[p];
        size_t bimg = (size_t)(p >> 18) * 3 * HWPIX + (p & (HWPIX - 1));
        float x0 = image[bimg];
        float x1 = image[bimg + HWPIX];
        float x2 = image[bimg + 2 * HWPIX];
        float x3 = 2.0f * lrv - 1.0f;
#pragma unroll
        for (int jc8 = 0; jc8 < 8; ++jc8) {
            int jc = jh * 8 + jc8;         // 16B chunk index (8 bf16)
            float h[8];
#pragma unroll
            for (int e = 0; e < 8; ++e) {
                int j = jc * 8 + e;        // SGPR-computable -> s_load
                float a = b1[j];
                a = fmaf(x0, w1[j], a);
                a = fmaf(x1, w1[128 + j], a);
                a = fmaf(x2, w1[256 + j], a);
                a = fmaf(x3, w1[384 + j], a);
                h[e] = fmaxf(a, 0.0f);
            }
            u32x4 pk = { pkbf(h[0], h[1]), pkbf(h[2], h[3]),
                         pkbf(h[4], h[5]), pkbf(h[6], h[7]) };
            int a = (((px << 8) | (jc << 4))) ^ ((px & 15) << 4);
            *(u32x4*)(lds + a) = pk;
        }
    }
    __syncthreads();

    // ---- phase 2: wave w computes rows [w*32, w*32+32) x all 128 cols ----
    int w    = t >> 6;
    int l    = t & 63;
    int lr16 = l & 15;
    int lh   = l >> 4;
    int rowbase = w * 32;

    // A-fragments from LDS (verified layout rounds 4-7)
    short8 af[2][4];
#pragma unroll
    for (int ks = 0; ks < 4; ++ks) {
#pragma unroll
        for (int mt = 0; mt < 2; ++mt) {
            int row = rowbase + mt * 16 + lr16;
            int a = (((row << 8) | (ks << 6) | (lh << 4))) ^ ((row & 15) << 4);
            af[mt][ks] = *(const short8*)(lds + a);
        }
    }

    float b2v[8], w3v[8];
#pragma unroll
    for (int jc = 0; jc < 8; ++jc) {
        int col = jc * 16 + lr16;
        b2v[jc] = b2[col];
        w3v[jc] = w3[col];
    }
    float b3v = b3[0];

    f32x4 acc[2][8];
#pragma unroll
    for (int mt = 0; mt < 2; ++mt)
#pragma unroll
        for (int jc = 0; jc < 8; ++jc)
            acc[mt][jc] = (f32x4){b2v[jc], b2v[jc], b2v[jc], b2v[jc]};  // b2 folded

    const short8* wf = (const short8*)w2f;
#pragma unroll
    for (int jc = 0; jc < 8; ++jc) {
        short8 bf[4];
#pragma unroll
        for (int ks = 0; ks < 4; ++ks) bf[ks] = wf[(jc * 4 + ks) * 64 + l];  // coalesced, L1-hot
#pragma unroll
        for (int ks = 0; ks < 4; ++ks) {
            acc[0][jc] = __builtin_amdgcn_mfma_f32_16x16x32_bf16(af[0][ks], bf[ks], acc[0][jc], 0, 0, 0);
            acc[1][jc] = __builtin_amdgcn_mfma_f32_16x16x32_bf16(af[1][ks], bf[ks], acc[1][jc], 0, 0, 0);
        }
    }

    // ---- epilogue: relu + dot(w3) reduce + sigmoid + select ----
#pragma unroll
    for (int mt = 0; mt < 2; ++mt) {
#pragma unroll
        for (int r = 0; r < 4; ++r) {
            int row = rowbase + mt * 16 + lh * 4 + r;   // C/D: row = (lane>>4)*4 + reg
            float part = 0.f;
#pragma unroll
            for (int jc = 0; jc < 8; ++jc)
                part += fmaxf(acc[mt][jc][r], 0.f) * w3v[jc];
            part += __shfl_xor(part, 1);
            part += __shfl_xor(part, 2);
            part += __shfl_xor(part, 4);
            part += __shfl_xor(part, 8);
            if (lr16 == 0) {
                int p = p0 + row;
                float lrv = lr[p];
                bool s = dm[p] && (goff[p >> 8] + (int)rankb[p] < PBUD);
                float logit = b3v + part;
                out[p] = s ? (1.0f / (1.0f + __expf(-logit))) : lrv;
            }
        }
    }
}

// ---------------- launcher ----------------------------------------------------
extern "C" void kernel_launch(void* const* d_in, const int* in_sizes, int n_in,
                              void* d_out, int out_size, void* d_ws, size_t ws_size,
                              hipStream_t stream) {
    const float* image = (const float*)d_in[0];
    const float* lr    = (const float*)d_in[1];
    const float* w1    = (const float*)d_in[2];
    const float* b1    = (const float*)d_in[3];
    const float* w2    = (const float*)d_in[4];
    const float* b2    = (const float*)d_in[5];
    const float* w3    = (const float*)d_in[6];
    const float* b3    = (const float*)d_in[7];
    float* out = (float*)d_out;

    char* ws = (char*)d_ws;
    unsigned char* rowdil = (unsigned char*)ws;                         // NPIX
    unsigned char* dm     = (unsigned char*)(ws + (size_t)NPIX);        // NPIX
    unsigned char* rankb  = (unsigned char*)(ws + 2 * (size_t)NPIX);    // NPIX
    int* gsum             = (int*)(ws + 3 * (size_t)NPIX);              // NB
    int* goff             = (int*)(ws + 3 * (size_t)NPIX + NB * 4);     // NB
    unsigned short* w2f   = (unsigned short*)(ws + 3 * (size_t)NPIX + 2 * NB * 4); // 16384 bf16

    k_prep_w2<<<64, 256, 0, stream>>>(w2, w2f);
    k_rowdil <<<NPIX / 256, 256, 0, stream>>>(lr, rowdil);
    k_coldil <<<NB, 256, 0, stream>>>(rowdil, dm, rankb, gsum);
    k_scan   <<<1, 1024, 0, stream>>>(gsum, goff);
    k_mlp    <<<NMLP, 256, 0, stream>>>(image, lr, w1, b1, w2f, b2, w3, b3,
                                        dm, rankb, goff, out);
}